// Round 7
// baseline (191.456 us; speedup 1.0000x reference)
//
#include <hip/hip_runtime.h>
#include <hip/hip_bf16.h>
#include <math.h>

typedef short short8 __attribute__((ext_vector_type(8)));
typedef float f32x4 __attribute__((ext_vector_type(4)));
typedef int i32x4 __attribute__((ext_vector_type(4)));

#define NN 8192
#define FIN 256
#define FOUT 128
#define LRELU_A 0.2f
#define L2E 1.44269504088896f

__device__ __forceinline__ short f2bf(float x) {
    unsigned u = __builtin_bit_cast(unsigned, x);
    unsigned r = (u + 0x7FFFu + ((u >> 16) & 1u)) >> 16;   // RNE
    return (short)r;
}

__device__ __forceinline__ void gload_lds16(const void* g, void* l) {
    __builtin_amdgcn_global_load_lds(
        (const __attribute__((address_space(1))) void*)g,
        (__attribute__((address_space(3))) void*)l, 16, 0, 0);
}

// K1: Wh = h @ W (fp32), fused f1 = Wh@a1, f2 = Wh@a2.
__global__ __launch_bounds__(256) void k_wh(const float* __restrict__ h,
                                            const float* __restrict__ W,
                                            const float* __restrict__ a,
                                            float* __restrict__ Wh,
                                            float* __restrict__ f1,
                                            float* __restrict__ f2) {
    __shared__ float hs[8][FIN];
    const int tid = threadIdx.x;
    const int r0 = blockIdx.x * 8;
    #pragma unroll
    for (int i = 0; i < 2; ++i) {
        int f4 = tid + 256 * i;              // 512 float4 total
        int row = f4 >> 6;
        int k4 = (f4 & 63) << 2;
        *(float4*)&hs[row][k4] = *(const float4*)(h + (size_t)(r0 + row) * FIN + k4);
    }
    __syncthreads();
    const int c4 = (tid & 31) * 4;
    const int row = tid >> 5;
    float acc0 = 0.f, acc1 = 0.f, acc2 = 0.f, acc3 = 0.f;
    #pragma unroll 4
    for (int k = 0; k < FIN; ++k) {
        float hv = hs[row][k];
        float4 w4 = *(const float4*)(W + (size_t)k * FOUT + c4);
        acc0 = fmaf(hv, w4.x, acc0);
        acc1 = fmaf(hv, w4.y, acc1);
        acc2 = fmaf(hv, w4.z, acc2);
        acc3 = fmaf(hv, w4.w, acc3);
    }
    float4 o; o.x = acc0; o.y = acc1; o.z = acc2; o.w = acc3;
    *(float4*)(Wh + (size_t)(r0 + row) * FOUT + c4) = o;

    float4 a1v = *(const float4*)(a + c4);
    float4 a2v = *(const float4*)(a + FOUT + c4);
    float p1 = acc0 * a1v.x + acc1 * a1v.y + acc2 * a1v.z + acc3 * a1v.w;
    float p2 = acc0 * a2v.x + acc1 * a2v.y + acc2 * a2v.z + acc3 * a2v.w;
    #pragma unroll
    for (int m = 1; m <= 16; m <<= 1) {
        p1 += __shfl_xor(p1, m, 64);
        p2 += __shfl_xor(p2, m, 64);
    }
    if ((tid & 31) == 0) {
        f1[r0 + row] = p1;
        f2[r0 + row] = p2;
    }
}

// K1t: WhT[c][r] = bf16(Wh[r][c]) via 32x32 LDS tiles.
__global__ __launch_bounds__(256) void k_transpose(const float* __restrict__ Wh,
                                                   short* __restrict__ WhT) {
    __shared__ float t32[32][33];
    const int tid = threadIdx.x;
    const int tx = tid & 31, ty = tid >> 5;
    const int rb = (blockIdx.x & 255) * 32;
    const int cb = (blockIdx.x >> 8) * 32;
    #pragma unroll
    for (int q = 0; q < 4; ++q) {
        int r = ty + q * 8;
        t32[r][tx] = Wh[(size_t)(rb + r) * FOUT + cb + tx];
    }
    __syncthreads();
    #pragma unroll
    for (int q = 0; q < 4; ++q) {
        int c = ty + q * 8;
        WhT[(size_t)(cb + c) * NN + rb + tx] = f2bf(t32[tx][c]);
    }
}

// K1c: gmax = max(f2)
__global__ __launch_bounds__(256) void k_gmax(const float* __restrict__ f2,
                                              float* __restrict__ gmax) {
    const int tid = threadIdx.x;
    float m = -1e30f;
    for (int i = tid; i < NN; i += 256) m = fmaxf(m, f2[i]);
    #pragma unroll
    for (int s = 1; s <= 32; s <<= 1) m = fmaxf(m, __shfl_xor(m, s, 64));
    __shared__ float red[4];
    if ((tid & 63) == 0) red[tid >> 6] = m;
    __syncthreads();
    if (tid == 0) gmax[0] = fmaxf(fmaxf(red[0], red[1]), fmaxf(red[2], red[3]));
}

__device__ __forceinline__ void gat_body(const short* __restrict__ lrd, unsigned m8,
                                         float4 fa, float4 fb,
                                         float f1r, float mh2, float& den,
                                         f32x4 acc[8]) {
    short8 b0 = *(const short8*)(lrd + 0 * 1024);
    short8 b1 = *(const short8*)(lrd + 1 * 1024);
    short8 b2 = *(const short8*)(lrd + 2 * 1024);
    short8 b3 = *(const short8*)(lrd + 3 * 1024);
    short8 b4 = *(const short8*)(lrd + 4 * 1024);
    short8 b5 = *(const short8*)(lrd + 5 * 1024);
    short8 b6 = *(const short8*)(lrd + 6 * 1024);
    short8 b7 = *(const short8*)(lrd + 7 * 1024);

    float fv[8] = {fa.x, fa.y, fa.z, fa.w, fb.x, fb.y, fb.z, fb.w};
    short8 af;
    #pragma unroll
    for (int i = 0; i < 8; ++i) {
        float e = f1r + fv[i];
        e = fmaxf(e, LRELU_A * e);
        float p = __builtin_amdgcn_exp2f(fmaf(e, L2E, -mh2));
        p = (m8 & (1u << i)) ? p : 0.0f;
        den += p;
        af[i] = f2bf(p);
    }
    acc[0] = __builtin_amdgcn_mfma_f32_16x16x32_bf16(af, b0, acc[0], 0, 0, 0);
    acc[1] = __builtin_amdgcn_mfma_f32_16x16x32_bf16(af, b1, acc[1], 0, 0, 0);
    acc[2] = __builtin_amdgcn_mfma_f32_16x16x32_bf16(af, b2, acc[2], 0, 0, 0);
    acc[3] = __builtin_amdgcn_mfma_f32_16x16x32_bf16(af, b3, acc[3], 0, 0, 0);
    acc[4] = __builtin_amdgcn_mfma_f32_16x16x32_bf16(af, b4, acc[4], 0, 0, 0);
    acc[5] = __builtin_amdgcn_mfma_f32_16x16x32_bf16(af, b5, acc[5], 0, 0, 0);
    acc[6] = __builtin_amdgcn_mfma_f32_16x16x32_bf16(af, b6, acc[6], 0, 0, 0);
    acc[7] = __builtin_amdgcn_mfma_f32_16x16x32_bf16(af, b7, acc[7], 0, 0, 0);
}

// Stage next 128x64 WhT tile into LDS buffer LB via global_load_lds:
// linear LDS dest (row*64 + slot*8 shorts), inverse-swizzled global source.
#define STAGE(LB, KC)                                          \
    do {                                                       \
        gload_lds16(gsrc0 + (KC),           (LB) + 0 * 512);   \
        gload_lds16(gsrc0 + (KC) + 8 * NN,  (LB) + 1 * 512);   \
        gload_lds16(gsrc0 + (KC) + 16 * NN, (LB) + 2 * 512);   \
        gload_lds16(gsrc0 + (KC) + 24 * NN, (LB) + 3 * 512);   \
    } while (0)

// One pipeline step. Issue order pinned with sched_barrier(0):
//   f2 (oldest) | load_lds next tile | adj prefetch (s+2, newest) | bodies.
// End-of-step: counted vmcnt(4) -> load_lds complete, the 4 adj prefetch
// loads stay in flight across the barrier.
#define GAT_STEP(KOFF, X0, X1, X2, X3, LRD0, LRD1, LWB)                            \
    {                                                                              \
        const int koff_ = (KOFF);                                                  \
        float4 fa0 = *(const float4*)(f2p + koff_);                                \
        float4 fb0 = *(const float4*)(f2p + koff_ + 4);                            \
        float4 fa1 = *(const float4*)(f2p + koff_ + 32);                           \
        float4 fb1 = *(const float4*)(f2p + koff_ + 36);                           \
        unsigned m0 = (unsigned)(X0.x & 1)        | ((unsigned)(X0.y & 1) << 1) |  \
                      ((unsigned)(X0.z & 1) << 2) | ((unsigned)(X0.w & 1) << 3) |  \
                      ((unsigned)(X1.x & 1) << 4) | ((unsigned)(X1.y & 1) << 5) |  \
                      ((unsigned)(X1.z & 1) << 6) | ((unsigned)(X1.w & 1) << 7);   \
        unsigned m1 = (unsigned)(X2.x & 1)        | ((unsigned)(X2.y & 1) << 1) |  \
                      ((unsigned)(X2.z & 1) << 2) | ((unsigned)(X2.w & 1) << 3) |  \
                      ((unsigned)(X3.x & 1) << 4) | ((unsigned)(X3.y & 1) << 5) |  \
                      ((unsigned)(X3.z & 1) << 6) | ((unsigned)(X3.w & 1) << 7);   \
        __builtin_amdgcn_sched_barrier(0);                                         \
        const int kst_ = (koff_ + 64 < kchunk) ? koff_ + 64 : 0;                   \
        STAGE(LWB, kst_);                                                          \
        __builtin_amdgcn_sched_barrier(0);                                         \
        const int kpre_ = (koff_ + 128 < kchunk) ? koff_ + 128 : 0;                \
        X0 = *(const i32x4*)(adjp + kpre_);                                        \
        X1 = *(const i32x4*)(adjp + kpre_ + 4);                                    \
        X2 = *(const i32x4*)(adjp + kpre_ + 32);                                   \
        X3 = *(const i32x4*)(adjp + kpre_ + 36);                                   \
        __builtin_amdgcn_sched_barrier(0);                                         \
        gat_body(LRD0, m0, fa0, fb0, f1r, mh2, den, acc);                          \
        gat_body(LRD1, m1, fa1, fb1, f1r, mh2, den, acc);                          \
        asm volatile("s_waitcnt vmcnt(4)" ::: "memory");                           \
        __builtin_amdgcn_s_barrier();                                              \
    }

// K2: fused mask + leaky_relu + exp + (P @ Wh) via mfma_f32_16x16x32_bf16.
// Raw adj stream (2-step-ahead reg prefetch) + double-buffered LDS WhT tile
// staged by global_load_lds (pre-swizzled source), counted-vmcnt barriers.
__global__ __launch_bounds__(256, 4) void k_attn(const int* __restrict__ adj,
                                                 const short* __restrict__ WhT,
                                                 const float* __restrict__ f1,
                                                 const float* __restrict__ f2,
                                                 const float* __restrict__ gmax,
                                                 float* __restrict__ numb,
                                                 float* __restrict__ denb,
                                                 int kchunk, int nsplit) {
    __shared__ __align__(16) short ldsW[2][8192];   // 2 x [128 rows][64 cols]
    const int tid = threadIdx.x;
    const int lane = tid & 63;
    const int wave = tid >> 6;
    const int split = blockIdx.x & (nsplit - 1);
    const int rt = blockIdx.x / nsplit;
    const int rowbase = rt * 64 + wave * 16;
    const int col = lane & 15;
    const int kg = lane >> 4;
    const int arow = rowbase + col;

    const float f1r = f1[arow];
    const float gm = gmax[0];
    const float t0v = f1r + gm;
    const float mhat = fmaxf(t0v, LRELU_A * t0v);   // row-max upper bound
    const float mh2 = mhat * L2E;

    const int kbase0 = split * kchunk;
    const float* f2p = f2 + kbase0 + kg * 8;
    const int* adjp = adj + (size_t)arow * NN + kbase0 + kg * 8;

    // global_load_lds source map: lane covers (row = 32*wave + 8*i + (lane>>3),
    // linear slot = lane&7); global col-block = slot ^ (row&7)  (involution)
    const int srow = lane >> 3;
    const int scol = (lane & 7) ^ srow;
    const short* gsrc0 = WhT + (size_t)(wave * 32 + srow) * NN + kbase0 + scol * 8;
    short* ldst0 = &ldsW[0][(wave * 32) * 64];
    short* ldst1 = &ldsW[1][(wave * 32) * 64];

    // compute-read bases (swizzled): slot = kg ^ (col&7), body1 slot ^= 4
    const short* lrdE0 = &ldsW[0][col * 64 + ((kg ^ (col & 7)) * 8)];
    const short* lrdE1 = &ldsW[0][col * 64 + (((kg ^ (col & 7)) * 8) ^ 32)];
    const short* lrdO0 = lrdE0 + 8192;
    const short* lrdO1 = lrdE1 + 8192;

    f32x4 acc[8] = {};
    float den = 0.0f;

    // prologue: stage tile 0 -> buf0; adj prefetch for steps 0 and 1
    STAGE(ldst0, 0);
    __builtin_amdgcn_sched_barrier(0);
    i32x4 xa0 = *(const i32x4*)(adjp + 0);
    i32x4 xa1 = *(const i32x4*)(adjp + 4);
    i32x4 xa2 = *(const i32x4*)(adjp + 32);
    i32x4 xa3 = *(const i32x4*)(adjp + 36);
    i32x4 xb0 = *(const i32x4*)(adjp + 64);
    i32x4 xb1 = *(const i32x4*)(adjp + 68);
    i32x4 xb2 = *(const i32x4*)(adjp + 96);
    i32x4 xb3 = *(const i32x4*)(adjp + 100);
    __builtin_amdgcn_sched_barrier(0);
    asm volatile("s_waitcnt vmcnt(8)" ::: "memory");   // tile0 done; 8 adj in flight
    __builtin_amdgcn_s_barrier();

    for (int koff = 0; koff < kchunk; koff += 128) {
        GAT_STEP(koff,      xa0, xa1, xa2, xa3, lrdE0, lrdE1, ldst1);  // read buf0, fill buf1
        GAT_STEP(koff + 64, xb0, xb1, xb2, xb3, lrdO0, lrdO1, ldst0);  // read buf1, fill buf0
    }

    // reduce den across the 4 kg groups
    den += __shfl_xor(den, 16, 64);
    den += __shfl_xor(den, 32, 64);
    if (lane < 16) denb[(size_t)split * NN + rowbase + lane] = den;

    float* np = numb + ((size_t)split * NN + rowbase) * FOUT;
    const int rsub = (lane >> 4) * 4;
    #pragma unroll
    for (int t = 0; t < 8; ++t) {
        #pragma unroll
        for (int r = 0; r < 4; ++r) {
            np[(size_t)(rsub + r) * FOUT + t * 16 + col] = acc[t][r];
        }
    }
}

// K3: sum split partials, divide, ELU.
__global__ __launch_bounds__(256) void k_final(const float* __restrict__ numb,
                                               const float* __restrict__ denb,
                                               float* __restrict__ out,
                                               int splitk) {
    const int idx = blockIdx.x * 256 + threadIdx.x;
    const int row = idx >> 7;
    float s = 0.0f, d = 0.0f;
    for (int sp = 0; sp < splitk; ++sp) {
        s += numb[((size_t)sp * NN) * FOUT + idx];
        d += denb[(size_t)sp * NN + row];
    }
    float v = s / d;
    out[idx] = v > 0.0f ? v : expm1f(v);
}

extern "C" void kernel_launch(void* const* d_in, const int* in_sizes, int n_in,
                              void* d_out, int out_size, void* d_ws, size_t ws_size,
                              hipStream_t stream) {
    const float* h = (const float*)d_in[0];
    const int* adj = (const int*)d_in[1];
    const float* W = (const float*)d_in[2];
    const float* a = (const float*)d_in[3];
    float* out = (float*)d_out;

    char* ws = (char*)d_ws;
    size_t off = 0;
    auto alloc = [&](size_t nbytes) {
        char* p = ws + off;
        off = (off + nbytes + 255) & ~(size_t)255;
        return p;
    };
    float* Wh  = (float*)alloc((size_t)NN * FOUT * 4);
    short* WhT = (short*)alloc((size_t)FOUT * NN * 2);
    float* f1  = (float*)alloc(NN * 4);
    float* f2  = (float*)alloc(NN * 4);
    float* gmx = (float*)alloc(256);

    int splitk = 8;
    while (splitk > 1 &&
           off + (size_t)splitk * ((size_t)NN * FOUT * 4 + NN * 4 + 512) > ws_size)
        splitk >>= 1;
    float* numb = (float*)alloc((size_t)splitk * NN * FOUT * 4);
    float* denb = (float*)alloc((size_t)splitk * NN * 4);
    const int kchunk = NN / splitk;

    k_wh<<<NN / 8, 256, 0, stream>>>(h, W, a, Wh, f1, f2);
    k_transpose<<<(NN / 32) * (FOUT / 32), 256, 0, stream>>>(Wh, WhT);
    k_gmax<<<1, 256, 0, stream>>>(f2, gmx);
    k_attn<<<(NN / 64) * splitk, 256, 0, stream>>>(adj, WhT, f1, f2, gmx, numb, denb,
                                                   kchunk, splitk);
    k_final<<<NN * FOUT / 256, 256, 0, stream>>>(numb, denb, out, splitk);
}